// Round 4
// baseline (531.990 us; speedup 1.0000x reference)
//
#include <hip/hip_runtime.h>
#include <hip/hip_bf16.h>
#include <math.h>

#define N_NODES 80000
#define N_EDGES 1280000
#define NCB 64
#define CB_DIV 1250                 // coarse bucket = dst / 1250 -> 0..63
#define CB_CAP 21000                // mean 20000, +7 sigma
#define NFB 1250                    // fine bucket = dst >> 6 (64 nodes each)
#define FB_CAP 1280                 // mean 1024, +8 sigma
#define EPB 1280                    // edges per k_part block (grid 1000)
#define ATS 20                      // aT leading-dim pad (16 nodes + 4)

typedef __hip_bfloat16 bf16;

__device__ __forceinline__ float leaky(float x) { return x >= 0.f ? x : 0.01f * x; }

union U4 { uint4 v; bf16 h[8]; };

// ---------------- setup kernels ----------------

__global__ void k_zero(float* bnsums, int* ctails, int* ftails) {
    int i = blockIdx.x * blockDim.x + threadIdx.x;
    if (i < 384) bnsums[i] = 0.f;
    if (i < NCB) ctails[i] = 0;
    if (i < NFB) ftails[i] = 0;
}

// pre-pack bf16 weight tiles for k_post64 (once per launch, 24 KB):
// pkw[0..511]    = lwT0[k][c]  (= lw0[c][k])
// pkw[512..1023] = w1[k][c]
// pkw[1024..1535]= lwT1[k][c]  (= lw1[c][k])
// NOTE: pkw overlays y3 (disjoint liveness: pkw dead before k_agg3 writes y3)
__global__ void k_packw(const float* __restrict__ lw0, const float* __restrict__ w1,
                        const float* __restrict__ lw1, uint4* __restrict__ pkw) {
    int i = blockIdx.x * 256 + threadIdx.x;
    if (i >= 1536) return;
    int set = i >> 9, r = i & 511;
    int k = r >> 3, cg = r & 7;
    U4 u;
    if (set == 0) {
#pragma unroll
        for (int j = 0; j < 8; ++j) u.h[j] = __float2bfloat16(lw0[(cg * 8 + j) * 64 + k]);
    } else if (set == 1) {
#pragma unroll
        for (int j = 0; j < 8; ++j) u.h[j] = __float2bfloat16(w1[k * 64 + cg * 8 + j]);
    } else {
#pragma unroll
        for (int j = 0; j < 8; ++j) u.h[j] = __float2bfloat16(lw1[(cg * 8 + j) * 64 + k]);
    }
    pkw[i] = u.v;
}

// pass 1: 64-way coarse bin of (src,dst) pairs; block bulk-reserves regions.
__global__ void __launch_bounds__(256)
k_part(const int* __restrict__ ei, int2* __restrict__ cpairs,
       int* __restrict__ ctails) {
    __shared__ int cnt[NCB], off[NCB];
    int t = threadIdx.x;
    if (t < NCB) cnt[t] = 0;
    __syncthreads();
    int base = blockIdx.x * EPB;
    int2 loc[5];
#pragma unroll
    for (int u = 0; u < 5; ++u) {
        int e = base + u * 256 + t;
        int s = ei[e], d = ei[N_EDGES + e];
        loc[u] = make_int2(s, d);
        atomicAdd(&cnt[d / CB_DIV], 1);
    }
    __syncthreads();
    if (t < NCB) off[t] = atomicAdd(&ctails[t], cnt[t]);
    __syncthreads();
#pragma unroll
    for (int u = 0; u < 5; ++u) {
        int b = loc[u].y / CB_DIV;
        int pos = atomicAdd(&off[b], 1);
        cpairs[(size_t)b * CB_CAP + pos] = loc[u];
    }
}

// pass 2: refine coarse bucket -> fine buckets of 64 nodes.
__global__ void __launch_bounds__(256)
k_refine(const int2* __restrict__ cpairs, const int* __restrict__ ctails,
         int* __restrict__ ftails, unsigned int* __restrict__ fpairs) {
    __shared__ int2 s_ed[2048];  // 16 KB strip stage
    __shared__ int cnt2[32], off2[32];
    int b = blockIdx.x & 63;
    int j = blockIdx.x >> 6;
    int t = threadIdx.x;
    int cnt = ctails[b];
    int s0 = j * 2048;
    if (s0 >= cnt) return;
    int n = min(2048, cnt - s0);
    int fb0 = (b * CB_DIV) >> 6;
    int nbins = (((b + 1) * CB_DIV - 1) >> 6) - fb0 + 1;  // <= 21
    const int2* lst = cpairs + (size_t)b * CB_CAP + s0;
    for (int i = t; i < n; i += 256) s_ed[i] = lst[i];
    if (t < 32) cnt2[t] = 0;
    __syncthreads();
    for (int i = t; i < n; i += 256)
        atomicAdd(&cnt2[(s_ed[i].y >> 6) - fb0], 1);
    __syncthreads();
    if (t < nbins && cnt2[t] > 0) off2[t] = atomicAdd(&ftails[fb0 + t], cnt2[t]);
    __syncthreads();
    for (int i = t; i < n; i += 256) {
        int2 pr = s_ed[i];
        int fbl = (pr.y >> 6) - fb0;
        int pos = atomicAdd(&off2[fbl], 1);
        fpairs[(size_t)(fb0 + fbl) * FB_CAP + pos] =
            (unsigned int)pr.x | ((unsigned int)(pr.y & 63) << 20);
    }
}

// single-block exclusive scan over ftails[1250] -> fbase (per-bucket CSR base).
__global__ void k_scanF(const int* __restrict__ ftails, int* __restrict__ fbase) {
    __shared__ int csum[256];
    int t = threadIdx.x;
    int loc[5];
    int sum = 0;
#pragma unroll
    for (int u = 0; u < 5; ++u) {
        int idx = t * 5 + u;
        int v = (idx < NFB) ? ftails[idx] : 0;
        loc[u] = sum;  // exclusive within this thread's chunk
        sum += v;
    }
    csum[t] = sum;
    __syncthreads();
    for (int off = 1; off < 256; off <<= 1) {
        int x = (t >= off) ? csum[t - off] : 0;
        __syncthreads();
        csum[t] += x;
        __syncthreads();
    }
    int base = (t > 0) ? csum[t - 1] : 0;
#pragma unroll
    for (int u = 0; u < 5; ++u) {
        int idx = t * 5 + u;
        if (idx < NFB) fbase[idx] = base + loc[u];
    }
}

// pass 3: per-fine-bucket LDS counting sort, then SEQUENTIAL CSR write.
// R14: emits src-only payload (src4, 4B/edge — dst implied by CSR position),
// plus per-node cursor and dinv.
__global__ void __launch_bounds__(256)
k_sortfine(const unsigned int* __restrict__ fpairs, const int* __restrict__ ftails,
           const int* __restrict__ fbase, int* __restrict__ src4,
           float* __restrict__ dinv, int* __restrict__ cursor) {
    __shared__ unsigned int stage[FB_CAP];
    __shared__ int hist[64], cur[64];
    int fb = blockIdx.x;
    int t = threadIdx.x;
    int cnt = ftails[fb];
    int base = fbase[fb];
    int node0 = fb * 64;
    const unsigned int* lst = fpairs + (size_t)fb * FB_CAP;
    if (t < 64) hist[t] = 0;
    __syncthreads();
    for (int i = t; i < cnt; i += 256)
        atomicAdd(&hist[lst[i] >> 20], 1);
    __syncthreads();
    if (t == 0) {
        int s = 0;
        for (int j = 0; j < 64; ++j) { cur[j] = s; s += hist[j]; }
    }
    __syncthreads();
    if (t < 64) {
        cursor[node0 + t] = base + cur[t];
        dinv[node0 + t] = rsqrtf((float)hist[t] + 2.0f);  // + self-loop weight 2
    }
    __syncthreads();  // cursor/dinv read cur before scatter mutates it
    for (int i = t; i < cnt; i += 256) {
        unsigned int r = lst[i];
        int p = atomicAdd(&cur[r >> 20], 1);
        stage[p] = r;
    }
    __syncthreads();
    for (int i = t; i < cnt; i += 256)
        src4[base + i] = (int)(stage[i] & 0xFFFFFu);
}

// h0 = x @ W0; hs = bf16(dinv*h0)  (R14: no yagg zero-init needed)
__global__ void k_h0s(const float* __restrict__ x, const float* __restrict__ W0,
                      const float* __restrict__ dinv, bf16* __restrict__ hs) {
    int tid = blockIdx.x * blockDim.x + threadIdx.x;
    if (tid < N_NODES * 64) {
        int v = tid >> 6, c = tid & 63;
        float x0 = x[v * 3], x1 = x[v * 3 + 1], x2 = x[v * 3 + 2];
        float h = x0 * W0[c] + x1 * W0[64 + c] + x2 * W0[128 + c];
        hs[tid] = __float2bfloat16(dinv[v] * h);
    }
}

// ---------------- per-stage kernels ----------------

// R14: wave-per-node CSR aggregation producing FINAL pre-BN y, with fused BN
// stats. lane == channel; srcs broadcast via v_readlane so addressing is
// scalar-pipe; 16 gathers in flight per node block. No atomics on y.
__global__ void __launch_bounds__(256)
k_aggn(const bf16* __restrict__ hs, const int* __restrict__ src4,
       const int* __restrict__ cursor, const float* __restrict__ dinv,
       const float* __restrict__ bias, float* __restrict__ y,
       float* __restrict__ bnsum) {
    int lane = threadIdx.x & 63;
    int w = threadIdx.x >> 6;
    float bc = bias[lane];
    float bs = 0.f, bss = 0.f;
    int nw = gridDim.x * 4;
    for (int v = blockIdx.x * 4 + w; v < N_NODES; v += nw) {
        int start = cursor[v];
        int end = (v + 1 < N_NODES) ? cursor[v + 1] : N_EDGES;
        float acc = 0.f;
        for (int eb = start; eb < end; eb += 16) {
            int idx = min(eb + (lane & 15), N_EDGES - 1);
            int sv = src4[idx];
            int nb = end - eb;  // >=16 except last block of row
#pragma unroll
            for (int u = 0; u < 16; ++u) {
                if (u < nb) {
                    int su = __builtin_amdgcn_readlane(sv, u);
                    acc += __bfloat162float(hs[(size_t)su * 64 + lane]);
                }
            }
        }
        float yv = fmaf(dinv[v], acc + 2.f * __bfloat162float(hs[(size_t)v * 64 + lane]), bc);
        y[(size_t)v * 64 + lane] = yv;
        bs += yv;
        bss += yv * yv;
    }
    __shared__ float s1[256], s2[256];
    s1[threadIdx.x] = bs;
    s2[threadIdx.x] = bss;
    __syncthreads();
    if (threadIdx.x < 64) {
        float t1 = s1[threadIdx.x] + s1[threadIdx.x + 64] + s1[threadIdx.x + 128] + s1[threadIdx.x + 192];
        float t2 = s2[threadIdx.x] + s2[threadIdx.x + 64] + s2[threadIdx.x + 128] + s2[threadIdx.x + 192];
        atomicAdd(&bnsum[threadIdx.x], t1);
        atomicAdd(&bnsum[64 + threadIdx.x], t2);
    }
}

// BN + maxpool + leaky + (a@lw.T+lb) + leaky + second matmul, register-tiled.
// 64-node tiles (grid 1250), 4 waves x 16-node subtiles, aT pad 20 ->
// 36.9 KB LDS = 4 blocks/CU = 16 waves/CU. R14: phase-1 reads only y
// (final pre-BN value from k_aggn) — no hs/bias re-read, no ZY.
template <int P, int MODE>
__global__ void __launch_bounds__(256)
k_post64(const float* __restrict__ y, const float* __restrict__ dinv,
         const float* __restrict__ bnsum,
         const float* __restrict__ g, const float* __restrict__ bb,
         const uint4* __restrict__ lwpk, const float* __restrict__ lb,
         const uint4* __restrict__ Wnpk, const float* __restrict__ Wnf,
         bf16* __restrict__ hsout, float4* __restrict__ hs3) {
    __shared__ float s_aT[4][64 * ATS];  // per-wave activation tile (transposed), reused as oT
    __shared__ uint4 s_lwT4[64 * 8];     // lwT bf16-packed: [k][cgroup]
    __shared__ uint4 s_Wn4[MODE == 0 ? 64 * 8 : 1];
    __shared__ float s_Wnf[MODE == 1 ? 64 * 3 : 1];
    int t = threadIdx.x;
    int w = t >> 6, lane = t & 63;
    for (int i = t; i < 512; i += 256) s_lwT4[i] = lwpk[i];
    if constexpr (MODE == 0) {
        for (int i = t; i < 512; i += 256) s_Wn4[i] = Wnpk[i];
    } else {
        for (int i = t; i < 64 * 3; i += 256) s_Wnf[i] = Wnf[i];
    }
    float inv_n = 1.0f / (float)N_NODES;
    float mean = bnsum[lane] * inv_n;
    float var = fmaxf(bnsum[64 + lane] * inv_n - mean * mean, 0.f);
    float sc = g[lane] * rsqrtf(var + 1e-5f);
    float sh = bb[lane] - mean * sc;
    int c0 = (lane >> 3) * 8, n0 = (lane & 7) * 2;
    int cg0 = lane >> 3;
    float lbv[8];
#pragma unroll
    for (int i = 0; i < 8; ++i) lbv[i] = lb[c0 + i];
    float* aT = s_aT[w];

    for (int tile = blockIdx.x; tile < N_NODES / 64; tile += gridDim.x) {
        int nbase = tile * 64 + w * 16;
        __syncthreads();  // covers weight-fill -> first use
#pragma unroll 4
        for (int i = 0; i < 16; ++i) {
            size_t idx = (size_t)(nbase + i) * 64 + lane;
            float z = fmaf(sc, y[idx], sh);
            float m = z;
#pragma unroll
            for (int d = 1; d <= P; ++d) {
                float up = __shfl(z, lane + d);
                float dn = __shfl(z, lane - d);
                m = fmaxf(m, (lane + d < 64) ? up : -INFINITY);
                m = fmaxf(m, (lane - d >= 0) ? dn : -INFINITY);
            }
            aT[lane * ATS + i] = leaky(m);
        }
        __syncthreads();
        // phase 2: o = leaky(a @ lw.T + lb)
        float acc[2][8];
#pragma unroll
        for (int nn = 0; nn < 2; ++nn)
#pragma unroll
            for (int i = 0; i < 8; ++i) acc[nn][i] = lbv[i];
#pragma unroll 8
        for (int k = 0; k < 64; ++k) {
            float2 av = *(const float2*)&aT[k * ATS + n0];
            U4 u; u.v = s_lwT4[k * 8 + cg0];
            float a2[2] = {av.x, av.y};
            float wv[8];
#pragma unroll
            for (int i = 0; i < 8; ++i) wv[i] = __bfloat162float(u.h[i]);
#pragma unroll
            for (int nn = 0; nn < 2; ++nn)
#pragma unroll
                for (int i = 0; i < 8; ++i) acc[nn][i] = fmaf(a2[nn], wv[i], acc[nn][i]);
        }
#pragma unroll
        for (int nn = 0; nn < 2; ++nn)
#pragma unroll
            for (int i = 0; i < 8; ++i) acc[nn][i] = leaky(acc[nn][i]);

        // write oT (aliases aT; same-wave LDS program order is safe)
#pragma unroll
        for (int i = 0; i < 8; ++i) {
            float2 ov = make_float2(acc[0][i], acc[1][i]);
            *(float2*)&aT[(c0 + i) * ATS + n0] = ov;
        }
        if constexpr (MODE == 0) {
            float acc2[2][8];
#pragma unroll
            for (int nn = 0; nn < 2; ++nn)
#pragma unroll
                for (int i = 0; i < 8; ++i) acc2[nn][i] = 0.f;
#pragma unroll 8
            for (int k = 0; k < 64; ++k) {
                float2 av = *(const float2*)&aT[k * ATS + n0];
                U4 u; u.v = s_Wn4[k * 8 + cg0];
                float a2[2] = {av.x, av.y};
                float wv[8];
#pragma unroll
                for (int i = 0; i < 8; ++i) wv[i] = __bfloat162float(u.h[i]);
#pragma unroll
                for (int nn = 0; nn < 2; ++nn)
#pragma unroll
                    for (int i = 0; i < 8; ++i) acc2[nn][i] = fmaf(a2[nn], wv[i], acc2[nn][i]);
            }
#pragma unroll
            for (int nn = 0; nn < 2; ++nn) {
                int node = nbase + n0 + nn;
                float dv = dinv[node];
                bf16 pk[8];
#pragma unroll
                for (int i = 0; i < 8; ++i) pk[i] = __float2bfloat16(dv * acc2[nn][i]);
                *(uint4*)&hsout[(size_t)node * 64 + c0] = *(uint4*)pk;
            }
        } else {
            // proj fused: h3 = o @ w2 (64x3); 8 lanes duplicate, c0==0 writes
            float acc3[2][3];
#pragma unroll
            for (int nn = 0; nn < 2; ++nn)
#pragma unroll
                for (int j = 0; j < 3; ++j) acc3[nn][j] = 0.f;
#pragma unroll 8
            for (int k = 0; k < 64; ++k) {
                float2 av = *(const float2*)&aT[k * ATS + n0];
                float a2[2] = {av.x, av.y};
                float w0 = s_Wnf[k * 3 + 0], w1 = s_Wnf[k * 3 + 1], w2v = s_Wnf[k * 3 + 2];
#pragma unroll
                for (int nn = 0; nn < 2; ++nn) {
                    acc3[nn][0] = fmaf(a2[nn], w0, acc3[nn][0]);
                    acc3[nn][1] = fmaf(a2[nn], w1, acc3[nn][1]);
                    acc3[nn][2] = fmaf(a2[nn], w2v, acc3[nn][2]);
                }
            }
            if (c0 == 0) {
#pragma unroll
                for (int nn = 0; nn < 2; ++nn) {
                    int node = nbase + n0 + nn;
                    float dv = dinv[node];
                    hs3[node] = make_float4(dv * acc3[nn][0], dv * acc3[nn][1],
                                            dv * acc3[nn][2], 0.f);
                }
            }
        }
    }
}

// stage-2: aggregation (thread-per-node over CSR rowstart) + final y3 + BN stats.
__global__ void __launch_bounds__(256)
k_agg3(const float4* __restrict__ hs3, const int* __restrict__ cursor,
       const int* __restrict__ src4, const float* __restrict__ dinv,
       const float* __restrict__ b2, float4* __restrict__ y3,
       float* __restrict__ bnsum) {
    int v = blockIdx.x * blockDim.x + threadIdx.x;
    float y0 = 0.f, y1 = 0.f, y2 = 0.f;
    bool valid = v < N_NODES;
    if (valid) {
        int start = cursor[v];
        int end = (v + 1 < N_NODES) ? cursor[v + 1] : N_EDGES;
        float a0 = 0.f, a1 = 0.f, a2 = 0.f;
        int e = start;
        for (; e + 4 <= end; e += 4) {
            int c[4];
#pragma unroll
            for (int u = 0; u < 4; ++u) c[u] = src4[e + u];
#pragma unroll
            for (int u = 0; u < 4; ++u) {
                float4 h = hs3[c[u]];
                a0 += h.x; a1 += h.y; a2 += h.z;
            }
        }
        for (; e < end; ++e) {
            float4 h = hs3[src4[e]];
            a0 += h.x; a1 += h.y; a2 += h.z;
        }
        float dv = dinv[v];
        float4 hsv = hs3[v];
        y0 = dv * (a0 + 2.f * hsv.x) + b2[0];
        y1 = dv * (a1 + 2.f * hsv.y) + b2[1];
        y2 = dv * (a2 + 2.f * hsv.z) + b2[2];
        y3[v] = make_float4(y0, y1, y2, 0.f);
    }
    __shared__ float sm[256];
    float vals[6] = {y0, y1, y2, y0 * y0, y1 * y1, y2 * y2};
    for (int c = 0; c < 6; ++c) {
        sm[threadIdx.x] = valid ? vals[c] : 0.f;
        __syncthreads();
        for (int off = 128; off > 0; off >>= 1) {
            if (threadIdx.x < off) sm[threadIdx.x] += sm[threadIdx.x + off];
            __syncthreads();
        }
        if (threadIdx.x == 0) atomicAdd(&bnsum[c], sm[0]);
        __syncthreads();
    }
}

// final stage post: BN + pool(3,1) + leaky + 3x3 linear + leaky
__global__ void k_post3(const float4* __restrict__ y3, const float* __restrict__ bnsum,
                        const float* __restrict__ g, const float* __restrict__ bb,
                        const float* __restrict__ lw, const float* __restrict__ lb,
                        float* __restrict__ out) {
    int v = blockIdx.x * blockDim.x + threadIdx.x;
    if (v >= N_NODES) return;
    float inv_n = 1.0f / (float)N_NODES;
    float sc[3], sh[3];
#pragma unroll
    for (int c = 0; c < 3; ++c) {
        float mean = bnsum[c] * inv_n;
        float var = fmaxf(bnsum[3 + c] * inv_n - mean * mean, 0.f);
        sc[c] = g[c] * rsqrtf(var + 1e-5f);
        sh[c] = bb[c] - mean * sc[c];
    }
    float4 y = y3[v];
    float z0 = fmaf(y.x, sc[0], sh[0]);
    float z1 = fmaf(y.y, sc[1], sh[1]);
    float z2 = fmaf(y.z, sc[2], sh[2]);
    float p0 = fmaxf(z0, z1);
    float p1 = fmaxf(p0, z2);
    float p2 = fmaxf(z1, z2);
    float a0 = leaky(p0), a1 = leaky(p1), a2 = leaky(p2);
    float o0 = leaky(lb[0] + a0 * lw[0] + a1 * lw[1] + a2 * lw[2]);
    float o1 = leaky(lb[1] + a0 * lw[3] + a1 * lw[4] + a2 * lw[5]);
    float o2 = leaky(lb[2] + a0 * lw[6] + a1 * lw[7] + a2 * lw[8]);
    out[v * 3 + 0] = o0;
    out[v * 3 + 1] = o1;
    out[v * 3 + 2] = o2;
}

// ---------------- launcher ----------------

extern "C" void kernel_launch(void* const* d_in, const int* in_sizes, int n_in,
                              void* d_out, int out_size, void* d_ws, size_t ws_size,
                              hipStream_t stream) {
    const float* x  = (const float*)d_in[0];
    const int*   ei = (const int*)d_in[1];
    const float* w0 = (const float*)d_in[2];
    const float* b0 = (const float*)d_in[3];
    const float* g0 = (const float*)d_in[4];
    const float* bb0 = (const float*)d_in[5];
    const float* lw0 = (const float*)d_in[6];
    const float* lb0 = (const float*)d_in[7];
    const float* w1 = (const float*)d_in[8];
    const float* b1 = (const float*)d_in[9];
    const float* g1 = (const float*)d_in[10];
    const float* bb1 = (const float*)d_in[11];
    const float* lw1 = (const float*)d_in[12];
    const float* lb1 = (const float*)d_in[13];
    const float* w2 = (const float*)d_in[14];
    const float* b2 = (const float*)d_in[15];
    const float* g2 = (const float*)d_in[16];
    const float* bb2 = (const float*)d_in[17];
    const float* lw2 = (const float*)d_in[18];
    const float* lb2 = (const float*)d_in[19];
    float* out = (float*)d_out;

    // workspace layout (16B-aligned first) — byte-identical to the 416us baseline
    char* w = (char*)d_ws;
    float* yagg = (float*)w;       w += (size_t)N_NODES * 64 * 4;        // 20.48 MB (y buffer)
    int* src4 = (int*)w;           w += (size_t)N_EDGES * 8;             // first 5.12MB of ex-ed2 slot
    unsigned int* fpairs = (unsigned int*)w; w += (size_t)NFB * FB_CAP * 4;  // 6.4 MB
    bf16* hs = (bf16*)w;           w += (size_t)N_NODES * 64 * 2;        // 10.24 MB
    float4* hs3 = (float4*)w;      w += (size_t)N_NODES * 16;            // 1.28 MB
    float4* y3 = (float4*)w;       w += (size_t)N_NODES * 16;            // 1.28 MB
    int* fbase = (int*)w;          w += (size_t)N_NODES * 4;             // (ex-deg slot; only 1250 used)
    float* dinv = (float*)w;       w += (size_t)N_NODES * 4;
    int* cursor = (int*)w;         w += (size_t)N_NODES * 4;
    int* partial = (int*)w;        w += 512 * 4;                         // unused (layout kept)
    float* bnsum = (float*)w;      w += 384 * 4;
    int* ctails = (int*)w;         w += NCB * 4;
    int* ftails = (int*)w;         w += NFB * 4;
    (void)partial;
    // cpairs overlays yagg (dead after k_refine, before k_aggn writes y)
    int2* cpairs = (int2*)yagg;
    // pkw overlays y3 (pkw last read in stage-1 k_post64; y3 first written by k_agg3)
    uint4* pkw = (uint4*)y3;

    const int NB = (N_NODES + 255) / 256;  // 313

    // --- graph/CSR setup: coarse bin -> refine -> ftails scan -> LDS sort -> CSR ---
    k_zero<<<5, 256, 0, stream>>>(bnsum, ctails, ftails);
    k_packw<<<6, 256, 0, stream>>>(lw0, w1, lw1, pkw);
    k_part<<<N_EDGES / EPB, 256, 0, stream>>>(ei, cpairs, ctails);
    k_refine<<<64 * 16, 256, 0, stream>>>(cpairs, ctails, ftails, fpairs);
    k_scanF<<<1, 256, 0, stream>>>(ftails, fbase);
    k_sortfine<<<NFB, 256, 0, stream>>>(fpairs, ftails, fbase, src4, dinv, cursor);

    // --- stage 0 ---
    k_h0s<<<(N_NODES * 64 + 255) / 256, 256, 0, stream>>>(x, w0, dinv, hs);
    k_aggn<<<1024, 256, 0, stream>>>(hs, src4, cursor, dinv, b0, yagg, bnsum);
    k_post64<1, 0><<<1250, 256, 0, stream>>>(yagg, dinv, bnsum, g0, bb0,
                                             pkw, lb0, pkw + 512, nullptr,
                                             hs, nullptr);

    // --- stage 1 ---
    k_aggn<<<1024, 256, 0, stream>>>(hs, src4, cursor, dinv, b1, yagg, bnsum + 128);
    k_post64<2, 1><<<1250, 256, 0, stream>>>(yagg, dinv, bnsum + 128, g1, bb1,
                                             pkw + 1024, lb1, nullptr, w2,
                                             nullptr, hs3);

    // --- stage 2 (C=3): agg + BN stats fused ---
    k_agg3<<<NB, 256, 0, stream>>>(hs3, cursor, src4, dinv, b2, y3, bnsum + 256);
    k_post3<<<NB, 256, 0, stream>>>(y3, bnsum + 256, g2, bb2, lw2, lb2, out);
}

// Round 5
// 366.982 us; speedup vs baseline: 1.4496x; 1.4496x over previous
//
#include <hip/hip_runtime.h>
#include <hip/hip_bf16.h>
#include <math.h>

#define N_NODES 80000
#define N_EDGES 1280000
#define CHUNK 128
#define N_CHUNKS (N_EDGES / CHUNK)  // 10000
#define NCB 64
#define CB_DIV 1250                 // coarse bucket = dst / 1250 -> 0..63
#define CB_CAP 21000                // mean 20000, +7 sigma
#define NFB 1250                    // fine bucket = dst >> 6 (64 nodes each)
#define FB_CAP 1280                 // mean 1024, +8 sigma
#define EPB 1280                    // edges per k_part block (grid 1000)
#define ATS 20                      // aT leading-dim pad (16 nodes + 4)

typedef __hip_bfloat16 bf16;

__device__ __forceinline__ float leaky(float x) { return x >= 0.f ? x : 0.01f * x; }

union U4 { uint4 v; bf16 h[8]; };

// ---------------- setup kernels ----------------

// R15: merged zero + weight-pack (one launch).
// pkw[0..511]    = lwT0[k][c]  (= lw0[c][k])
// pkw[512..1023] = w1[k][c]
// pkw[1024..1535]= lwT1[k][c]  (= lw1[c][k])
// NOTE: pkw overlays y3 (disjoint liveness: pkw dead before k_agg3 writes y3)
__global__ void k_init(float* bnsums, int* ctails, int* ftails,
                       const float* __restrict__ lw0, const float* __restrict__ w1,
                       const float* __restrict__ lw1, uint4* __restrict__ pkw) {
    int i = blockIdx.x * 256 + threadIdx.x;
    if (i < 384) bnsums[i] = 0.f;
    if (i < NCB) ctails[i] = 0;
    if (i < NFB) ftails[i] = 0;
    if (i >= 1536) return;
    int set = i >> 9, r = i & 511;
    int k = r >> 3, cg = r & 7;
    U4 u;
    if (set == 0) {
#pragma unroll
        for (int j = 0; j < 8; ++j) u.h[j] = __float2bfloat16(lw0[(cg * 8 + j) * 64 + k]);
    } else if (set == 1) {
#pragma unroll
        for (int j = 0; j < 8; ++j) u.h[j] = __float2bfloat16(w1[k * 64 + cg * 8 + j]);
    } else {
#pragma unroll
        for (int j = 0; j < 8; ++j) u.h[j] = __float2bfloat16(lw1[(cg * 8 + j) * 64 + k]);
    }
    pkw[i] = u.v;
}

// pass 1: 64-way coarse bin of (src,dst) pairs; block bulk-reserves regions.
__global__ void __launch_bounds__(256)
k_part(const int* __restrict__ ei, int2* __restrict__ cpairs,
       int* __restrict__ ctails) {
    __shared__ int cnt[NCB], off[NCB];
    int t = threadIdx.x;
    if (t < NCB) cnt[t] = 0;
    __syncthreads();
    int base = blockIdx.x * EPB;
    int2 loc[5];
#pragma unroll
    for (int u = 0; u < 5; ++u) {
        int e = base + u * 256 + t;
        int s = ei[e], d = ei[N_EDGES + e];
        loc[u] = make_int2(s, d);
        atomicAdd(&cnt[d / CB_DIV], 1);
    }
    __syncthreads();
    if (t < NCB) off[t] = atomicAdd(&ctails[t], cnt[t]);
    __syncthreads();
#pragma unroll
    for (int u = 0; u < 5; ++u) {
        int b = loc[u].y / CB_DIV;
        int pos = atomicAdd(&off[b], 1);
        cpairs[(size_t)b * CB_CAP + pos] = loc[u];
    }
}

// pass 2: refine coarse bucket -> fine buckets of 64 nodes.
// R15: LDS-compacted output — entries are compacted per-bin in LDS, then each
// bin's run is copied out as a contiguous coalesced range (reservation base
// off2 is no longer used as a mutable cursor). Kills the ~8x write-amp of the
// previous 4B scatter (R12: WRITE_SIZE 39 MB vs 5.1 MB ideal).
__global__ void __launch_bounds__(256)
k_refine(const int2* __restrict__ cpairs, const int* __restrict__ ctails,
         int* __restrict__ ftails, unsigned int* __restrict__ fpairs) {
    __shared__ int2 s_ed[2048];          // 16 KB strip stage
    __shared__ unsigned int s_comp[2048];// 8 KB compacted output
    __shared__ int cnt2[32], off2[32], lcl[32], lpos[32];
    int b = blockIdx.x & 63;
    int j = blockIdx.x >> 6;
    int t = threadIdx.x;
    int cnt = ctails[b];
    int s0 = j * 2048;
    if (s0 >= cnt) return;
    int n = min(2048, cnt - s0);
    int fb0 = (b * CB_DIV) >> 6;
    int nbins = (((b + 1) * CB_DIV - 1) >> 6) - fb0 + 1;  // <= 21
    const int2* lst = cpairs + (size_t)b * CB_CAP + s0;
    for (int i = t; i < n; i += 256) s_ed[i] = lst[i];
    if (t < 32) cnt2[t] = 0;
    __syncthreads();
    for (int i = t; i < n; i += 256)
        atomicAdd(&cnt2[(s_ed[i].y >> 6) - fb0], 1);
    __syncthreads();
    if (t == 0) {
        int s = 0;
        for (int q = 0; q < nbins; ++q) { lcl[q] = s; s += cnt2[q]; }
    }
    if (t < nbins && cnt2[t] > 0) off2[t] = atomicAdd(&ftails[fb0 + t], cnt2[t]);
    __syncthreads();
    if (t < nbins) lpos[t] = lcl[t];
    __syncthreads();
    for (int i = t; i < n; i += 256) {
        int2 pr = s_ed[i];
        int fbl = (pr.y >> 6) - fb0;
        int p = atomicAdd(&lpos[fbl], 1);
        s_comp[p] = (unsigned int)pr.x | ((unsigned int)(pr.y & 63) << 20);
    }
    __syncthreads();
    // coalesced copy-out: wave wv handles bins wv, wv+4, ...
    int wv = t >> 6, ln = t & 63;
    for (int q = wv; q < nbins; q += 4) {
        int c = cnt2[q];
        if (c == 0) continue;
        unsigned int* dst = fpairs + (size_t)(fb0 + q) * FB_CAP + off2[q];
        const unsigned int* src = s_comp + lcl[q];
        for (int i = ln; i < c; i += 64) dst[i] = src[i];
    }
}

// single-block exclusive scan over ftails[1250] -> fbase (per-bucket CSR base).
__global__ void k_scanF(const int* __restrict__ ftails, int* __restrict__ fbase) {
    __shared__ int csum[256];
    int t = threadIdx.x;
    int loc[5];
    int sum = 0;
#pragma unroll
    for (int u = 0; u < 5; ++u) {
        int idx = t * 5 + u;
        int v = (idx < NFB) ? ftails[idx] : 0;
        loc[u] = sum;  // exclusive within this thread's chunk
        sum += v;
    }
    csum[t] = sum;
    __syncthreads();
    for (int off = 1; off < 256; off <<= 1) {
        int x = (t >= off) ? csum[t - off] : 0;
        __syncthreads();
        csum[t] += x;
        __syncthreads();
    }
    int base = (t > 0) ? csum[t - 1] : 0;
#pragma unroll
    for (int u = 0; u < 5; ++u) {
        int idx = t * 5 + u;
        if (idx < NFB) fbase[idx] = base + loc[u];
    }
}

// pass 3: per-fine-bucket LDS counting sort, then SEQUENTIAL CSR write.
// Emits ed2 records plus per-node cursor and dinv (rsqrt(deg+2)).
__global__ void __launch_bounds__(256)
k_sortfine(const unsigned int* __restrict__ fpairs, const int* __restrict__ ftails,
           const int* __restrict__ fbase, int2* __restrict__ ed2,
           float* __restrict__ dinv, int* __restrict__ cursor) {
    __shared__ unsigned int stage[FB_CAP];
    __shared__ int hist[64], cur[64];
    int fb = blockIdx.x;
    int t = threadIdx.x;
    int cnt = ftails[fb];
    int base = fbase[fb];
    int node0 = fb * 64;
    const unsigned int* lst = fpairs + (size_t)fb * FB_CAP;
    if (t < 64) hist[t] = 0;
    __syncthreads();
    for (int i = t; i < cnt; i += 256)
        atomicAdd(&hist[lst[i] >> 20], 1);
    __syncthreads();
    if (t == 0) {
        int s = 0;
        for (int j = 0; j < 64; ++j) { cur[j] = s; s += hist[j]; }
    }
    __syncthreads();
    if (t < 64) {
        cursor[node0 + t] = base + cur[t];
        dinv[node0 + t] = rsqrtf((float)hist[t] + 2.0f);  // + self-loop weight 2
    }
    __syncthreads();  // cursor/dinv read cur before scatter mutates it
    for (int i = t; i < cnt; i += 256) {
        unsigned int r = lst[i];
        int p = atomicAdd(&cur[r >> 20], 1);
        stage[p] = r;
    }
    __syncthreads();
    for (int i = t; i < cnt; i += 256) {
        unsigned int r = stage[i];
        ed2[base + i] = make_int2((int)(r & 0xFFFFFu), node0 + (int)(r >> 20));
    }
}

// h0 = x @ W0; hs = bf16(dinv*h0); also zero-inits yagg
__global__ void k_h0s(const float* __restrict__ x, const float* __restrict__ W0,
                      const float* __restrict__ dinv, bf16* __restrict__ hs,
                      float* __restrict__ yagg) {
    int tid = blockIdx.x * blockDim.x + threadIdx.x;
    if (tid < N_NODES * 64) {
        int v = tid >> 6, c = tid & 63;
        float x0 = x[v * 3], x1 = x[v * 3 + 1], x2 = x[v * 3 + 2];
        float h = x0 * W0[c] + x1 * W0[64 + c] + x2 * W0[128 + c];
        hs[tid] = __float2bfloat16(dinv[v] * h);
        yagg[tid] = 0.f;
    }
}

// ---------------- per-stage kernels ----------------

// segmented edge-stream aggregation over CSR-sorted records (R10 structure).
__global__ void __launch_bounds__(256)
k_agg_seg(const bf16* __restrict__ hs, const int2* __restrict__ ed2,
          float* __restrict__ yagg) {
    int lane = threadIdx.x & 63;
    int wid = (blockIdx.x * blockDim.x + threadIdx.x) >> 6;
    if (wid >= N_CHUNKS) return;
    int e = wid * CHUNK;
    int2 c[8];
#pragma unroll
    for (int u = 0; u < 8; ++u) c[u] = ed2[e + u];
    float acc = 0.f;
    int cur = __builtin_amdgcn_readfirstlane(c[0].y);
    bool lead = true;
    for (int b = 0; b < CHUNK / 8; ++b) {
        float pv[8];
#pragma unroll
        for (int u = 0; u < 8; ++u)
            pv[u] = __bfloat162float(hs[(size_t)c[u].x * 64 + lane]);
        int2 cn[8];
        if (b < CHUNK / 8 - 1) {
            int en = e + 8;
#pragma unroll
            for (int u = 0; u < 8; ++u) cn[u] = ed2[en + u];
        }
#pragma unroll
        for (int u = 0; u < 8; ++u) {
            int du = __builtin_amdgcn_readfirstlane(c[u].y);
            if (du != cur) {
                if (lead) {
                    atomicAdd(&yagg[(size_t)cur * 64 + lane], acc);
                    lead = false;
                } else {
                    yagg[(size_t)cur * 64 + lane] = acc;  // exclusive owner
                }
                acc = 0.f;
                cur = du;
            }
            acc += pv[u];
        }
        e += 8;
        if (b < CHUNK / 8 - 1) {
#pragma unroll
            for (int u = 0; u < 8; ++u) c[u] = cn[u];
        }
    }
    atomicAdd(&yagg[(size_t)cur * 64 + lane], acc);  // trailing: may straddle
}

// per-channel sum/sumsq of y_final = dinv[v]*(yagg + 2*hs_self) + bias[c]
__global__ void __launch_bounds__(256)
k_bnstats(const float* __restrict__ yagg, const bf16* __restrict__ hs,
          const float* __restrict__ dinv, const float* __restrict__ bias,
          float* __restrict__ bnsum) {
    int tid = blockIdx.x * blockDim.x + threadIdx.x;
    int stride = gridDim.x * blockDim.x;  // multiple of 64 -> lane == channel
    float bc = bias[tid & 63];
    float bs = 0.f, bss = 0.f;
    for (size_t i = tid; i < (size_t)N_NODES * 64; i += stride) {
        float comb = yagg[i] + 2.f * __bfloat162float(hs[i]);
        float yf = dinv[i >> 6] * comb + bc;
        bs += yf;
        bss += yf * yf;
    }
    __shared__ float s1[256], s2[256];
    s1[threadIdx.x] = bs;
    s2[threadIdx.x] = bss;
    __syncthreads();
    if (threadIdx.x < 64) {
        float t1 = s1[threadIdx.x] + s1[threadIdx.x + 64] + s1[threadIdx.x + 128] + s1[threadIdx.x + 192];
        float t2 = s2[threadIdx.x] + s2[threadIdx.x + 64] + s2[threadIdx.x + 128] + s2[threadIdx.x + 192];
        atomicAdd(&bnsum[threadIdx.x], t1);
        atomicAdd(&bnsum[64 + threadIdx.x], t2);
    }
}

// BN + maxpool + leaky + (a@lw.T+lb) + leaky + second matmul, register-tiled.
// 64-node tiles (grid 1250), 4 waves x 16-node subtiles, aT pad 20 ->
// 36.9 KB LDS = 4 blocks/CU = 16 waves/CU.
// Weights arrive pre-packed bf16 (k_init) -> coalesced uint4 prologue.
template <int P, int MODE, bool ZY>
__global__ void __launch_bounds__(256)
k_post64(float* __restrict__ yagg, const bf16* __restrict__ hs,
         const float* __restrict__ dinv, const float* __restrict__ bias,
         const float* __restrict__ bnsum,
         const float* __restrict__ g, const float* __restrict__ bb,
         const uint4* __restrict__ lwpk, const float* __restrict__ lb,
         const uint4* __restrict__ Wnpk, const float* __restrict__ Wnf,
         bf16* __restrict__ hsout, float4* __restrict__ hs3) {
    __shared__ float s_aT[4][64 * ATS];  // per-wave activation tile (transposed), reused as oT
    __shared__ uint4 s_lwT4[64 * 8];     // lwT bf16-packed: [k][cgroup]
    __shared__ uint4 s_Wn4[MODE == 0 ? 64 * 8 : 1];
    __shared__ float s_Wnf[MODE == 1 ? 64 * 3 : 1];
    int t = threadIdx.x;
    int w = t >> 6, lane = t & 63;
    for (int i = t; i < 512; i += 256) s_lwT4[i] = lwpk[i];
    if constexpr (MODE == 0) {
        for (int i = t; i < 512; i += 256) s_Wn4[i] = Wnpk[i];
    } else {
        for (int i = t; i < 64 * 3; i += 256) s_Wnf[i] = Wnf[i];
    }
    float inv_n = 1.0f / (float)N_NODES;
    float mean = bnsum[lane] * inv_n;
    float var = fmaxf(bnsum[64 + lane] * inv_n - mean * mean, 0.f);
    float sc = g[lane] * rsqrtf(var + 1e-5f);
    float sh = bb[lane] - mean * sc;
    float shb = fmaf(sc, bias[lane], sh);  // folds GCN bias into BN shift
    int c0 = (lane >> 3) * 8, n0 = (lane & 7) * 2;
    int cg0 = lane >> 3;
    float lbv[8];
#pragma unroll
    for (int i = 0; i < 8; ++i) lbv[i] = lb[c0 + i];
    float* aT = s_aT[w];

    for (int tile = blockIdx.x; tile < N_NODES / 64; tile += gridDim.x) {
        int nbase = tile * 64 + w * 16;
        __syncthreads();  // covers weight-fill -> first use
#pragma unroll 4
        for (int i = 0; i < 16; ++i) {
            size_t idx = (size_t)(nbase + i) * 64 + lane;
            float comb = yagg[idx] + 2.f * __bfloat162float(hs[idx]);
            if (ZY) yagg[idx] = 0.f;  // element is dead after this read
            float z = fmaf(sc * dinv[nbase + i], comb, shb);
            float m = z;
#pragma unroll
            for (int d = 1; d <= P; ++d) {
                float up = __shfl(z, lane + d);
                float dn = __shfl(z, lane - d);
                m = fmaxf(m, (lane + d < 64) ? up : -INFINITY);
                m = fmaxf(m, (lane - d >= 0) ? dn : -INFINITY);
            }
            aT[lane * ATS + i] = leaky(m);
        }
        __syncthreads();
        // phase 2: o = leaky(a @ lw.T + lb)
        float acc[2][8];
#pragma unroll
        for (int nn = 0; nn < 2; ++nn)
#pragma unroll
            for (int i = 0; i < 8; ++i) acc[nn][i] = lbv[i];
#pragma unroll 8
        for (int k = 0; k < 64; ++k) {
            float2 av = *(const float2*)&aT[k * ATS + n0];
            U4 u; u.v = s_lwT4[k * 8 + cg0];
            float a2[2] = {av.x, av.y};
            float wv[8];
#pragma unroll
            for (int i = 0; i < 8; ++i) wv[i] = __bfloat162float(u.h[i]);
#pragma unroll
            for (int nn = 0; nn < 2; ++nn)
#pragma unroll
                for (int i = 0; i < 8; ++i) acc[nn][i] = fmaf(a2[nn], wv[i], acc[nn][i]);
        }
#pragma unroll
        for (int nn = 0; nn < 2; ++nn)
#pragma unroll
            for (int i = 0; i < 8; ++i) acc[nn][i] = leaky(acc[nn][i]);

        // write oT (aliases aT; same-wave LDS program order is safe)
#pragma unroll
        for (int i = 0; i < 8; ++i) {
            float2 ov = make_float2(acc[0][i], acc[1][i]);
            *(float2*)&aT[(c0 + i) * ATS + n0] = ov;
        }
        if constexpr (MODE == 0) {
            float acc2[2][8];
#pragma unroll
            for (int nn = 0; nn < 2; ++nn)
#pragma unroll
                for (int i = 0; i < 8; ++i) acc2[nn][i] = 0.f;
#pragma unroll 8
            for (int k = 0; k < 64; ++k) {
                float2 av = *(const float2*)&aT[k * ATS + n0];
                U4 u; u.v = s_Wn4[k * 8 + cg0];
                float a2[2] = {av.x, av.y};
                float wv[8];
#pragma unroll
                for (int i = 0; i < 8; ++i) wv[i] = __bfloat162float(u.h[i]);
#pragma unroll
                for (int nn = 0; nn < 2; ++nn)
#pragma unroll
                    for (int i = 0; i < 8; ++i) acc2[nn][i] = fmaf(a2[nn], wv[i], acc2[nn][i]);
            }
#pragma unroll
            for (int nn = 0; nn < 2; ++nn) {
                int node = nbase + n0 + nn;
                float dv = dinv[node];
                bf16 pk[8];
#pragma unroll
                for (int i = 0; i < 8; ++i) pk[i] = __float2bfloat16(dv * acc2[nn][i]);
                *(uint4*)&hsout[(size_t)node * 64 + c0] = *(uint4*)pk;
            }
        } else {
            // proj fused: h3 = o @ w2 (64x3); 8 lanes duplicate, c0==0 writes
            float acc3[2][3];
#pragma unroll
            for (int nn = 0; nn < 2; ++nn)
#pragma unroll
                for (int j = 0; j < 3; ++j) acc3[nn][j] = 0.f;
#pragma unroll 8
            for (int k = 0; k < 64; ++k) {
                float2 av = *(const float2*)&aT[k * ATS + n0];
                float a2[2] = {av.x, av.y};
                float w0 = s_Wnf[k * 3 + 0], w1 = s_Wnf[k * 3 + 1], w2v = s_Wnf[k * 3 + 2];
#pragma unroll
                for (int nn = 0; nn < 2; ++nn) {
                    acc3[nn][0] = fmaf(a2[nn], w0, acc3[nn][0]);
                    acc3[nn][1] = fmaf(a2[nn], w1, acc3[nn][1]);
                    acc3[nn][2] = fmaf(a2[nn], w2v, acc3[nn][2]);
                }
            }
            if (c0 == 0) {
#pragma unroll
                for (int nn = 0; nn < 2; ++nn) {
                    int node = nbase + n0 + nn;
                    float dv = dinv[node];
                    hs3[node] = make_float4(dv * acc3[nn][0], dv * acc3[nn][1],
                                            dv * acc3[nn][2], 0.f);
                }
            }
        }
    }
}

// stage-2: aggregation (thread-per-node over CSR rowstart) + final y3 + BN stats.
__global__ void __launch_bounds__(256)
k_agg3(const float4* __restrict__ hs3, const int* __restrict__ cursor,
       const int2* __restrict__ ed2, const float* __restrict__ dinv,
       const float* __restrict__ b2, float4* __restrict__ y3,
       float* __restrict__ bnsum) {
    int v = blockIdx.x * blockDim.x + threadIdx.x;
    float y0 = 0.f, y1 = 0.f, y2 = 0.f;
    bool valid = v < N_NODES;
    if (valid) {
        int start = cursor[v];
        int end = (v + 1 < N_NODES) ? cursor[v + 1] : N_EDGES;
        float a0 = 0.f, a1 = 0.f, a2 = 0.f;
        int e = start;
        for (; e + 4 <= end; e += 4) {
            int2 c[4];
#pragma unroll
            for (int u = 0; u < 4; ++u) c[u] = ed2[e + u];
#pragma unroll
            for (int u = 0; u < 4; ++u) {
                float4 h = hs3[c[u].x];
                a0 += h.x; a1 += h.y; a2 += h.z;
            }
        }
        for (; e < end; ++e) {
            float4 h = hs3[ed2[e].x];
            a0 += h.x; a1 += h.y; a2 += h.z;
        }
        float dv = dinv[v];
        float4 hsv = hs3[v];
        y0 = dv * (a0 + 2.f * hsv.x) + b2[0];
        y1 = dv * (a1 + 2.f * hsv.y) + b2[1];
        y2 = dv * (a2 + 2.f * hsv.z) + b2[2];
        y3[v] = make_float4(y0, y1, y2, 0.f);
    }
    __shared__ float sm[256];
    float vals[6] = {y0, y1, y2, y0 * y0, y1 * y1, y2 * y2};
    for (int c = 0; c < 6; ++c) {
        sm[threadIdx.x] = valid ? vals[c] : 0.f;
        __syncthreads();
        for (int off = 128; off > 0; off >>= 1) {
            if (threadIdx.x < off) sm[threadIdx.x] += sm[threadIdx.x + off];
            __syncthreads();
        }
        if (threadIdx.x == 0) atomicAdd(&bnsum[c], sm[0]);
        __syncthreads();
    }
}

// final stage post: BN + pool(3,1) + leaky + 3x3 linear + leaky
__global__ void k_post3(const float4* __restrict__ y3, const float* __restrict__ bnsum,
                        const float* __restrict__ g, const float* __restrict__ bb,
                        const float* __restrict__ lw, const float* __restrict__ lb,
                        float* __restrict__ out) {
    int v = blockIdx.x * blockDim.x + threadIdx.x;
    if (v >= N_NODES) return;
    float inv_n = 1.0f / (float)N_NODES;
    float sc[3], sh[3];
#pragma unroll
    for (int c = 0; c < 3; ++c) {
        float mean = bnsum[c] * inv_n;
        float var = fmaxf(bnsum[3 + c] * inv_n - mean * mean, 0.f);
        sc[c] = g[c] * rsqrtf(var + 1e-5f);
        sh[c] = bb[c] - mean * sc[c];
    }
    float4 y = y3[v];
    float z0 = fmaf(y.x, sc[0], sh[0]);
    float z1 = fmaf(y.y, sc[1], sh[1]);
    float z2 = fmaf(y.z, sc[2], sh[2]);
    float p0 = fmaxf(z0, z1);
    float p1 = fmaxf(p0, z2);
    float p2 = fmaxf(z1, z2);
    float a0 = leaky(p0), a1 = leaky(p1), a2 = leaky(p2);
    float o0 = leaky(lb[0] + a0 * lw[0] + a1 * lw[1] + a2 * lw[2]);
    float o1 = leaky(lb[1] + a0 * lw[3] + a1 * lw[4] + a2 * lw[5]);
    float o2 = leaky(lb[2] + a0 * lw[6] + a1 * lw[7] + a2 * lw[8]);
    out[v * 3 + 0] = o0;
    out[v * 3 + 1] = o1;
    out[v * 3 + 2] = o2;
}

// ---------------- launcher ----------------

extern "C" void kernel_launch(void* const* d_in, const int* in_sizes, int n_in,
                              void* d_out, int out_size, void* d_ws, size_t ws_size,
                              hipStream_t stream) {
    const float* x  = (const float*)d_in[0];
    const int*   ei = (const int*)d_in[1];
    const float* w0 = (const float*)d_in[2];
    const float* b0 = (const float*)d_in[3];
    const float* g0 = (const float*)d_in[4];
    const float* bb0 = (const float*)d_in[5];
    const float* lw0 = (const float*)d_in[6];
    const float* lb0 = (const float*)d_in[7];
    const float* w1 = (const float*)d_in[8];
    const float* b1 = (const float*)d_in[9];
    const float* g1 = (const float*)d_in[10];
    const float* bb1 = (const float*)d_in[11];
    const float* lw1 = (const float*)d_in[12];
    const float* lb1 = (const float*)d_in[13];
    const float* w2 = (const float*)d_in[14];
    const float* b2 = (const float*)d_in[15];
    const float* g2 = (const float*)d_in[16];
    const float* bb2 = (const float*)d_in[17];
    const float* lw2 = (const float*)d_in[18];
    const float* lb2 = (const float*)d_in[19];
    float* out = (float*)d_out;

    // workspace layout (16B-aligned first) — byte-identical to the 416us baseline
    char* w = (char*)d_ws;
    float* yagg = (float*)w;       w += (size_t)N_NODES * 64 * 4;        // 20.48 MB
    int2* ed2 = (int2*)w;          w += (size_t)N_EDGES * 8;             // 10.24 MB
    unsigned int* fpairs = (unsigned int*)w; w += (size_t)NFB * FB_CAP * 4;  // 6.4 MB
    bf16* hs = (bf16*)w;           w += (size_t)N_NODES * 64 * 2;        // 10.24 MB
    float4* hs3 = (float4*)w;      w += (size_t)N_NODES * 16;            // 1.28 MB
    float4* y3 = (float4*)w;       w += (size_t)N_NODES * 16;            // 1.28 MB
    int* fbase = (int*)w;          w += (size_t)N_NODES * 4;             // (ex-deg slot; only 1250 used)
    float* dinv = (float*)w;       w += (size_t)N_NODES * 4;
    int* cursor = (int*)w;         w += (size_t)N_NODES * 4;
    int* partial = (int*)w;        w += 512 * 4;                         // unused (layout kept)
    float* bnsum = (float*)w;      w += 384 * 4;
    int* ctails = (int*)w;         w += NCB * 4;
    int* ftails = (int*)w;         w += NFB * 4;
    (void)partial;
    // cpairs overlays yagg (dead after k_refine, before k_h0s zero-inits yagg)
    int2* cpairs = (int2*)yagg;
    // pkw overlays y3 (pkw last read in stage-1 k_post64; y3 first written by k_agg3)
    uint4* pkw = (uint4*)y3;

    const int NB = (N_NODES + 255) / 256;  // 313

    // --- graph/CSR setup: coarse bin -> refine -> ftails scan -> LDS sort -> CSR ---
    k_init<<<6, 256, 0, stream>>>(bnsum, ctails, ftails, lw0, w1, lw1, pkw);
    k_part<<<N_EDGES / EPB, 256, 0, stream>>>(ei, cpairs, ctails);
    k_refine<<<64 * 16, 256, 0, stream>>>(cpairs, ctails, ftails, fpairs);
    k_scanF<<<1, 256, 0, stream>>>(ftails, fbase);
    k_sortfine<<<NFB, 256, 0, stream>>>(fpairs, ftails, fbase, ed2, dinv, cursor);

    // --- stage 0 ---
    k_h0s<<<(N_NODES * 64 + 255) / 256, 256, 0, stream>>>(x, w0, dinv, hs, yagg);
    k_agg_seg<<<2500, 256, 0, stream>>>(hs, ed2, yagg);
    k_bnstats<<<640, 256, 0, stream>>>(yagg, hs, dinv, b0, bnsum);
    // ZY=true: re-zeroes yagg for stage 1 while reading it
    k_post64<1, 0, true><<<1250, 256, 0, stream>>>(yagg, hs, dinv, b0, bnsum, g0, bb0,
                                                   pkw, lb0, pkw + 512, nullptr,
                                                   hs, nullptr);

    // --- stage 1 ---
    k_agg_seg<<<2500, 256, 0, stream>>>(hs, ed2, yagg);
    k_bnstats<<<640, 256, 0, stream>>>(yagg, hs, dinv, b1, bnsum + 128);
    k_post64<2, 1, false><<<1250, 256, 0, stream>>>(yagg, hs, dinv, b1, bnsum + 128, g1, bb1,
                                                    pkw + 1024, lb1, nullptr, w2,
                                                    nullptr, hs3);

    // --- stage 2 (C=3): agg + BN stats fused ---
    k_agg3<<<NB, 256, 0, stream>>>(hs3, cursor, ed2, dinv, b2, y3, bnsum + 256);
    k_post3<<<NB, 256, 0, stream>>>(y3, bnsum + 256, g2, bb2, lw2, lb2, out);
}